// Round 1
// baseline (356.147 us; speedup 1.0000x reference)
//
#include <hip/hip_runtime.h>
#include <hip/hip_bf16.h>

// EdgeGNN: 3x EdgeConv(mean) + final linear.
// Algebraic reduction: per-node  out_i = cat([h_i, mean_nbr - h_i]) @ W + b  (0 if deg==0)
// => gather-mean (CSR) + node-level bf16 MFMA GEMM instead of edge-level GEMM (10x FLOPs).

typedef short short8 __attribute__((ext_vector_type(8)));
typedef float float4v __attribute__((ext_vector_type(4)));

static __device__ __forceinline__ float bf2f(unsigned short u) {
    union { unsigned int i; float f; } c; c.i = ((unsigned int)u) << 16; return c.f;
}
static __device__ __forceinline__ unsigned short f2bf(float f) {
    union { float f; unsigned int i; } c; c.f = f;
    unsigned int u = c.i;
    return (unsigned short)((u + 0x7FFFu + ((u >> 16) & 1u)) >> 16);  // RNE
}

// ---------------- CSR build ----------------
__global__ void count_kernel(const int* __restrict__ dst, int E, int* __restrict__ deg) {
    int idx = blockIdx.x * 256 + threadIdx.x;
    if (idx < E) atomicAdd(&deg[dst[idx]], 1);
}

__global__ __launch_bounds__(1024) void scan_kernel(const int* __restrict__ deg,
                                                    int* __restrict__ offs,
                                                    int* __restrict__ cursor, int N) {
    __shared__ int sh[1024];
    int t = threadIdx.x;
    int CH = (N + 1023) >> 10;
    int beg = t * CH, end = beg + CH; if (end > N) end = N; if (beg > N) beg = N;
    int s = 0;
    for (int i = beg; i < end; ++i) s += deg[i];
    sh[t] = s;
    __syncthreads();
    for (int off = 1; off < 1024; off <<= 1) {
        int v = 0;
        if (t >= off) v = sh[t - off];
        __syncthreads();
        if (t >= off) sh[t] += v;
        __syncthreads();
    }
    int run = (t > 0) ? sh[t - 1] : 0;
    for (int i = beg; i < end; ++i) {
        offs[i] = run; cursor[i] = run; run += deg[i];
    }
    if (t == 1023) offs[N] = sh[1023];
}

__global__ void fill_kernel(const int* __restrict__ src, const int* __restrict__ dst, int E,
                            int* __restrict__ cursor, int* __restrict__ esrc) {
    int idx = blockIdx.x * 256 + threadIdx.x;
    if (idx < E) {
        int p = atomicAdd(&cursor[dst[idx]], 1);
        esrc[p] = src[idx];
    }
}

// ---------------- weight transpose + bf16 convert:  Wt[n][k] = bf16(W[k][n]) ----------------
__global__ void wt_kernel(const float* __restrict__ W, unsigned short* __restrict__ Wt, int K) {
    int idx = blockIdx.x * 256 + threadIdx.x;
    if (idx < K * 256) {
        int n = idx / K, k = idx - n * K;
        Wt[idx] = f2bf(W[k * 256 + n]);
    }
}

// x fp32 -> bf16 into Ucat column block 0 (row stride 1024)
__global__ void cvtx_kernel(const float* __restrict__ x, unsigned short* __restrict__ Ucat, int N) {
    int idx = blockIdx.x * 256 + threadIdx.x;
    if (idx < N * 256) {
        int i = idx >> 8, c = idx & 255;
        Ucat[(long)i * 1024 + c] = f2bf(x[idx]);
    }
}

// ---------------- neighbor mean: one wave per node ----------------
// H = Ucat + l*256 (bf16 rows, stride 1024). Writes U[i] = [h_i, mean - h_i] (bf16, [N][512]).
__global__ __launch_bounds__(64)
void agg_kernel(const unsigned short* __restrict__ H,
                const int* __restrict__ offs, const int* __restrict__ esrc,
                unsigned short* __restrict__ U, int N) {
    int i = blockIdx.x;
    int lane = threadIdx.x;
    const unsigned short* hp = H + (long)i * 1024 + lane * 4;
    ushort4 own = *(const ushort4*)hp;
    float o0 = bf2f(own.x), o1 = bf2f(own.y), o2 = bf2f(own.z), o3 = bf2f(own.w);
    float a0 = 0.f, a1 = 0.f, a2 = 0.f, a3 = 0.f;
    int e0 = offs[i], e1 = offs[i + 1];
    int e = e0;
    for (; e + 2 <= e1; e += 2) {  // 2-way unroll for MLP
        int s0 = esrc[e], s1 = esrc[e + 1];
        ushort4 r0 = *(const ushort4*)(H + (long)s0 * 1024 + lane * 4);
        ushort4 r1 = *(const ushort4*)(H + (long)s1 * 1024 + lane * 4);
        a0 += bf2f(r0.x) + bf2f(r1.x);
        a1 += bf2f(r0.y) + bf2f(r1.y);
        a2 += bf2f(r0.z) + bf2f(r1.z);
        a3 += bf2f(r0.w) + bf2f(r1.w);
    }
    if (e < e1) {
        int s0 = esrc[e];
        ushort4 r0 = *(const ushort4*)(H + (long)s0 * 1024 + lane * 4);
        a0 += bf2f(r0.x); a1 += bf2f(r0.y); a2 += bf2f(r0.z); a3 += bf2f(r0.w);
    }
    int d = e1 - e0;
    float inv = (d > 0) ? 1.0f / (float)d : 0.0f;
    unsigned short* up = U + (long)i * 512 + lane * 4;
    *(ushort4*)up = own;
    ushort4 w;
    w.x = f2bf(a0 * inv - o0);
    w.y = f2bf(a1 * inv - o1);
    w.z = f2bf(a2 * inv - o2);
    w.w = f2bf(a3 * inv - o3);
    *(ushort4*)(up + 256) = w;
}

// ---------------- bf16 MFMA GEMM: C[M,256] = A[M,K] @ Bt[256,K]^T + bias ----------------
// MODE 0: layer  -> relu, zero rows with deg==0, write bf16 into Ucat (stride 1024, +colOff)
// MODE 1: final  -> write fp32 to out (stride 256)
#define BM 128
#define BN 128
#define BK 32
#define LDK 40  // padded LDS row stride (elements); 80B rows => 2-way bank aliasing (free)

template <int MODE>
__global__ __launch_bounds__(256)
void gemm_kernel(const unsigned short* __restrict__ A,
                 const unsigned short* __restrict__ Bt,
                 const float* __restrict__ bias,
                 const int* __restrict__ deg,
                 unsigned short* __restrict__ outB,
                 float* __restrict__ outF,
                 int M, int K, int colOff) {
    __shared__ unsigned short ldsA[BM * LDK];
    __shared__ unsigned short ldsB[BN * LDK];
    int t = threadIdx.x;
    int bm = blockIdx.x, bn = blockIdx.y;
    int lane = t & 63, wave = t >> 6;
    int wm = wave >> 1, wn = wave & 1;
    int lr = lane & 15, q = lane >> 4;

    float4v acc[4][4];
#pragma unroll
    for (int i = 0; i < 4; i++)
#pragma unroll
        for (int j = 0; j < 4; j++) { float4v z = {0.f, 0.f, 0.f, 0.f}; acc[i][j] = z; }

    int r = t >> 1;       // 0..127: staging row
    int half = t & 1;     // which 32B half of the 64B row-slice
    bool okA = (bm * BM + r) < M;
    const unsigned short* gA = A + (long)(bm * BM + r) * K + half * 16;
    const unsigned short* gB = Bt + (long)(bn * BN + r) * K + half * 16;
    unsigned short* sA = ldsA + r * LDK + half * 16;
    unsigned short* sB = ldsB + r * LDK + half * 16;

    for (int k0 = 0; k0 < K; k0 += BK) {
        uint4 a0 = make_uint4(0, 0, 0, 0), a1 = a0;
        if (okA) {
            a0 = *(const uint4*)(gA + k0);
            a1 = *(const uint4*)(gA + k0 + 8);
        }
        uint4 b0 = *(const uint4*)(gB + k0);
        uint4 b1 = *(const uint4*)(gB + k0 + 8);
        __syncthreads();
        *(uint4*)(sA) = a0; *(uint4*)(sA + 8) = a1;
        *(uint4*)(sB) = b0; *(uint4*)(sB + 8) = b1;
        __syncthreads();
        short8 af[4], bf8[4];
#pragma unroll
        for (int mi = 0; mi < 4; ++mi)
            af[mi] = *(const short8*)(ldsA + (wm * 64 + mi * 16 + lr) * LDK + q * 8);
#pragma unroll
        for (int ni = 0; ni < 4; ++ni)
            bf8[ni] = *(const short8*)(ldsB + (wn * 64 + ni * 16 + lr) * LDK + q * 8);
#pragma unroll
        for (int mi = 0; mi < 4; ++mi)
#pragma unroll
            for (int ni = 0; ni < 4; ++ni)
                acc[mi][ni] = __builtin_amdgcn_mfma_f32_16x16x32_bf16(af[mi], bf8[ni], acc[mi][ni], 0, 0, 0);
    }

    int colBase = bn * BN + wn * 64;
    int rowBase = bm * BM + wm * 64;
#pragma unroll
    for (int mi = 0; mi < 4; ++mi) {
#pragma unroll
        for (int ni = 0; ni < 4; ++ni) {
            int col = colBase + ni * 16 + lr;
            float bv = bias[col];
            int row0 = rowBase + mi * 16 + q * 4;
#pragma unroll
            for (int rr4 = 0; rr4 < 4; ++rr4) {
                int rr = row0 + rr4;
                if (rr < M) {
                    float v = acc[mi][ni][rr4] + bv;
                    if (MODE == 0) {
                        v = fmaxf(v, 0.0f);
                        if (deg[rr] <= 0) v = 0.0f;
                        outB[(long)rr * 1024 + colOff + col] = f2bf(v);
                    } else {
                        outF[(long)rr * 256 + col] = v;
                    }
                }
            }
        }
    }
}

extern "C" void kernel_launch(void* const* d_in, const int* in_sizes, int n_in,
                              void* d_out, int out_size, void* d_ws, size_t ws_size,
                              hipStream_t stream) {
    const float* x = (const float*)d_in[0];
    const int* ei = (const int*)d_in[1];
    const float* W[3] = {(const float*)d_in[2], (const float*)d_in[4], (const float*)d_in[6]};
    const float* b[3] = {(const float*)d_in[3], (const float*)d_in[5], (const float*)d_in[7]};
    const float* Wfp = (const float*)d_in[8];
    const float* bfp = (const float*)d_in[9];

    int N = in_sizes[0] / 256;
    int E = in_sizes[1] / 2;
    const int* src = ei;
    const int* dst = ei + E;

    char* p = (char*)d_ws;
    auto alloc = [&](size_t bytes) { char* r = p; p += (bytes + 255) & ~(size_t)255; return r; };
    int* deg = (int*)alloc((size_t)N * 4);
    int* offs = (int*)alloc((size_t)(N + 1) * 4);
    int* cursor = (int*)alloc((size_t)N * 4);
    int* esrc = (int*)alloc((size_t)E * 4);
    unsigned short* Wt[3];
    for (int l = 0; l < 3; l++) Wt[l] = (unsigned short*)alloc(256 * 512 * 2);
    unsigned short* Wtf = (unsigned short*)alloc(256 * 1024 * 2);
    unsigned short* U = (unsigned short*)alloc((size_t)N * 512 * 2);
    unsigned short* Ucat = (unsigned short*)alloc((size_t)N * 1024 * 2);

    hipMemsetAsync(deg, 0, (size_t)N * 4, stream);
    int eb = (E + 255) / 256;
    count_kernel<<<eb, 256, 0, stream>>>(dst, E, deg);
    scan_kernel<<<1, 1024, 0, stream>>>(deg, offs, cursor, N);
    fill_kernel<<<eb, 256, 0, stream>>>(src, dst, E, cursor, esrc);
    for (int l = 0; l < 3; l++)
        wt_kernel<<<(512 * 256 + 255) / 256, 256, 0, stream>>>(W[l], Wt[l], 512);
    wt_kernel<<<(1024 * 256 + 255) / 256, 256, 0, stream>>>(Wfp, Wtf, 1024);
    cvtx_kernel<<<(N * 256 + 255) / 256, 256, 0, stream>>>(x, Ucat, N);

    int gm = (N + BM - 1) / BM;
    for (int l = 0; l < 3; l++) {
        agg_kernel<<<N, 64, 0, stream>>>(Ucat + l * 256, offs, esrc, U, N);
        gemm_kernel<0><<<dim3(gm, 2), 256, 0, stream>>>(U, Wt[l], b[l], deg, Ucat, nullptr,
                                                        N, 512, (l + 1) * 256);
    }
    gemm_kernel<1><<<dim3(gm, 2), 256, 0, stream>>>(Ucat, Wtf, bfp, nullptr, nullptr,
                                                    (float*)d_out, N, 1024, 0);
}